// Round 10
// baseline (34.088 us; speedup 1.0000x reference)
//
#include <hip/hip_runtime.h>

typedef __attribute__((ext_vector_type(8))) short bf16x8;
typedef __attribute__((ext_vector_type(4))) float f32x4;
typedef __attribute__((ext_vector_type(2))) float f32x2;

// Native cast -> v_cvt_pk_bf16_f32 on gfx950 (RNE).
__device__ __forceinline__ unsigned short f2bf(float x) {
    union { __bf16 h; unsigned short s; } u;
    u.h = (__bf16)x;
    return u.s;
}

// K1: fused skinny GEMMs (R4 structure verbatim), bf16 epilogue w/ cpw folded.
// *** MEASUREMENT ROUND: launched TWICE (idempotent) to expose gemm time in
// *** dur_us: gemm ~= dur - 22.6us(R9) - ~2.5us dispatch overhead.
__global__ __launch_bounds__(256) void gemm_fused(
    const float* __restrict__ hs, const float* __restrict__ seqW,
    const float* __restrict__ hidW, const float* __restrict__ cpw,
    unsigned short* __restrict__ E16 /* [2][4096][32] bf16 */)
{
    __shared__ float red[4][16][32];

    const int bid = blockIdx.x;
    const bool hid = bid >= 256;
    const int mt  = hid ? bid - 256 : bid;
    const int tid = threadIdx.x;
    const int wv  = tid >> 6;
    const int l   = tid & 63;
    const int l15 = l & 15;
    const int g   = l >> 4;
    const int m0  = mt * 16;
    const int mrow = m0 + l15;

    const float* __restrict__ W = hid ? hidW : seqW;
    size_t arow;
    if (hid) arow = ((size_t)(mrow >> 10) << 20) + (size_t)(mrow & 1023);
    else     arow = (size_t)mrow << 10;

    f32x4 acc0 = {0.f,0.f,0.f,0.f}, acc1 = {0.f,0.f,0.f,0.f};
    const int kbase = wv * 256;

    for (int ks = 0; ks < 8; ++ks) {
        const int kb = kbase + ks * 32 + g * 8;
        bf16x8 af, bf0, bf1;
        if (hid) {
            const float* pa = hs + arow + (size_t)kb * 1024;
            float a[8];
            #pragma unroll
            for (int j = 0; j < 8; ++j) a[j] = pa[(size_t)j * 1024];
            #pragma unroll
            for (int j = 0; j < 8; ++j) af[j] = (short)f2bf(a[j]);
        } else {
            const f32x4* pa = (const f32x4*)(hs + arow + kb);
            f32x4 a0 = pa[0], a1 = pa[1];
            af[0]=(short)f2bf(a0.x); af[1]=(short)f2bf(a0.y); af[2]=(short)f2bf(a0.z); af[3]=(short)f2bf(a0.w);
            af[4]=(short)f2bf(a1.x); af[5]=(short)f2bf(a1.y); af[6]=(short)f2bf(a1.z); af[7]=(short)f2bf(a1.w);
        }
        {
            const f32x4* pb = (const f32x4*)(W + (size_t)l15 * 1024 + kb);
            f32x4 b0 = pb[0], b1 = pb[1];
            bf0[0]=(short)f2bf(b0.x); bf0[1]=(short)f2bf(b0.y); bf0[2]=(short)f2bf(b0.z); bf0[3]=(short)f2bf(b0.w);
            bf0[4]=(short)f2bf(b1.x); bf0[5]=(short)f2bf(b1.y); bf0[6]=(short)f2bf(b1.z); bf0[7]=(short)f2bf(b1.w);
        }
        {
            const f32x4* pb = (const f32x4*)(W + (size_t)(l15 + 16) * 1024 + kb);
            f32x4 b0 = pb[0], b1 = pb[1];
            bf1[0]=(short)f2bf(b0.x); bf1[1]=(short)f2bf(b0.y); bf1[2]=(short)f2bf(b0.z); bf1[3]=(short)f2bf(b0.w);
            bf1[4]=(short)f2bf(b1.x); bf1[5]=(short)f2bf(b1.y); bf1[6]=(short)f2bf(b1.z); bf1[7]=(short)f2bf(b1.w);
        }
        acc0 = __builtin_amdgcn_mfma_f32_16x16x32_bf16(af, bf0, acc0, 0, 0, 0);
        acc1 = __builtin_amdgcn_mfma_f32_16x16x32_bf16(af, bf1, acc1, 0, 0, 0);
    }

    // C/D layout (m89-verified): col = lane&15, row = (lane>>4)*4 + reg
    #pragma unroll
    for (int r = 0; r < 4; ++r) {
        red[wv][4 * g + r][l15]      = acc0[r];
        red[wv][4 * g + r][l15 + 16] = acc1[r];
    }
    __syncthreads();

    // Sum 4 wave-partials -> fold cpw (seq only) -> bf16 pack -> 4B store.
    const int o = tid * 2;
    const float* rf = &red[0][0][0];
    float vx = rf[o]     + rf[512 + o]     + rf[1024 + o]     + rf[1536 + o];
    float vy = rf[o + 1] + rf[512 + o + 1] + rf[1024 + o + 1] + rf[1536 + o + 1];
    if (!hid) {
        f32x2 w = *(const f32x2*)(cpw + (o & 31));
        vx *= w.x; vy *= w.y;
    }
    unsigned pk = (unsigned)f2bf(vx) | ((unsigned)f2bf(vy) << 16);
    unsigned short* Eo = E16 + (hid ? (size_t)4096 * 32 : 0) + (size_t)m0 * 32 + o;
    *(unsigned*)Eo = pk;
}

// K3: rank-32 GEMM via MFMA, zero LDS (R9 verbatim).
__global__ __launch_bounds__(256) void k3(const unsigned short* __restrict__ E16,
                                          float* __restrict__ out)
{
    const int tid = threadIdx.x;
    const int wv  = tid >> 6;
    const int l   = tid & 63;
    const int l15 = l & 15;
    const int g   = l >> 4;
    const int b   = blockIdx.z;
    const int s0  = blockIdx.y * 128 + wv * 32;
    const int h0  = blockIdx.x * 64;

    const unsigned short* As = E16 + ((size_t)(b * 1024 + s0)) * 32;
    const unsigned short* Bh = E16 + (size_t)4096 * 32 + ((size_t)(b * 1024 + h0)) * 32;

    bf16x8 af[2], bfr[4];
    #pragma unroll
    for (int i = 0; i < 2; ++i)
        af[i] = *(const bf16x8*)(As + (size_t)(i * 16 + l15) * 32 + g * 8);
    #pragma unroll
    for (int j = 0; j < 4; ++j)
        bfr[j] = *(const bf16x8*)(Bh + (size_t)(j * 16 + l15) * 32 + g * 8);

    const f32x4 zero = {0.f, 0.f, 0.f, 0.f};
    f32x4 acc[2][4];
    #pragma unroll
    for (int i = 0; i < 2; ++i)
        #pragma unroll
        for (int j = 0; j < 4; ++j)
            acc[i][j] = __builtin_amdgcn_mfma_f32_16x16x32_bf16(af[i], bfr[j], zero, 0, 0, 0);

    #pragma unroll
    for (int i = 0; i < 2; ++i)
        #pragma unroll
        for (int r = 0; r < 4; ++r) {
            float* orow = out + ((size_t)(b * 1024 + s0 + i * 16 + 4 * g + r)) * 1024 + h0;
            #pragma unroll
            for (int j = 0; j < 4; ++j)
                orow[j * 16 + l15] = acc[i][j][r];
        }
}

extern "C" void kernel_launch(void* const* d_in, const int* in_sizes, int n_in,
                              void* d_out, int out_size, void* d_ws, size_t ws_size,
                              hipStream_t stream) {
    const float* hs   = (const float*)d_in[0];
    // d_in[1] = all_indices: identically (n/H, n%H) -> computed implicitly
    const float* seqW = (const float*)d_in[2];
    const float* hidW = (const float*)d_in[3];
    const float* cpw  = (const float*)d_in[4];
    float* out = (float*)d_out;

    unsigned short* E16 = (unsigned short*)d_ws;   // [2][4096][32] bf16, 512 KB

    // MEASUREMENT: double-launch the (idempotent) gemm to expose its duration.
    gemm_fused<<<512, 256, 0, stream>>>(hs, seqW, hidW, cpw, E16);
    gemm_fused<<<512, 256, 0, stream>>>(hs, seqW, hidW, cpw, E16);
    dim3 grid3(16, 8, 4);
    k3<<<grid3, 256, 0, stream>>>(E16, out);
}

// Round 11
// 23.386 us; speedup vs baseline: 1.4577x; 1.4577x over previous
//
#include <hip/hip_runtime.h>

typedef __attribute__((ext_vector_type(8))) short bf16x8;
typedef __attribute__((ext_vector_type(4))) float f32x4;
typedef __attribute__((ext_vector_type(2))) float f32x2;

// Native cast -> v_cvt_pk_bf16_f32 on gfx950 (RNE).
__device__ __forceinline__ unsigned short f2bf(float x) {
    union { __bf16 h; unsigned short s; } u;
    u.h = (__bf16)x;
    return u.s;
}

// K1: fused skinny GEMMs (R4 structure verbatim), bf16 epilogue w/ cpw folded.
// Measured R10: gemm ~= 10us (vs 5.2us traffic floor) -> next round's target.
__global__ __launch_bounds__(256) void gemm_fused(
    const float* __restrict__ hs, const float* __restrict__ seqW,
    const float* __restrict__ hidW, const float* __restrict__ cpw,
    unsigned short* __restrict__ E16 /* [2][4096][32] bf16 */)
{
    __shared__ float red[4][16][32];

    const int bid = blockIdx.x;
    const bool hid = bid >= 256;
    const int mt  = hid ? bid - 256 : bid;
    const int tid = threadIdx.x;
    const int wv  = tid >> 6;
    const int l   = tid & 63;
    const int l15 = l & 15;
    const int g   = l >> 4;
    const int m0  = mt * 16;
    const int mrow = m0 + l15;

    const float* __restrict__ W = hid ? hidW : seqW;
    size_t arow;
    if (hid) arow = ((size_t)(mrow >> 10) << 20) + (size_t)(mrow & 1023);
    else     arow = (size_t)mrow << 10;

    f32x4 acc0 = {0.f,0.f,0.f,0.f}, acc1 = {0.f,0.f,0.f,0.f};
    const int kbase = wv * 256;

    for (int ks = 0; ks < 8; ++ks) {
        const int kb = kbase + ks * 32 + g * 8;
        bf16x8 af, bf0, bf1;
        if (hid) {
            const float* pa = hs + arow + (size_t)kb * 1024;
            float a[8];
            #pragma unroll
            for (int j = 0; j < 8; ++j) a[j] = pa[(size_t)j * 1024];
            #pragma unroll
            for (int j = 0; j < 8; ++j) af[j] = (short)f2bf(a[j]);
        } else {
            const f32x4* pa = (const f32x4*)(hs + arow + kb);
            f32x4 a0 = pa[0], a1 = pa[1];
            af[0]=(short)f2bf(a0.x); af[1]=(short)f2bf(a0.y); af[2]=(short)f2bf(a0.z); af[3]=(short)f2bf(a0.w);
            af[4]=(short)f2bf(a1.x); af[5]=(short)f2bf(a1.y); af[6]=(short)f2bf(a1.z); af[7]=(short)f2bf(a1.w);
        }
        {
            const f32x4* pb = (const f32x4*)(W + (size_t)l15 * 1024 + kb);
            f32x4 b0 = pb[0], b1 = pb[1];
            bf0[0]=(short)f2bf(b0.x); bf0[1]=(short)f2bf(b0.y); bf0[2]=(short)f2bf(b0.z); bf0[3]=(short)f2bf(b0.w);
            bf0[4]=(short)f2bf(b1.x); bf0[5]=(short)f2bf(b1.y); bf0[6]=(short)f2bf(b1.z); bf0[7]=(short)f2bf(b1.w);
        }
        {
            const f32x4* pb = (const f32x4*)(W + (size_t)(l15 + 16) * 1024 + kb);
            f32x4 b0 = pb[0], b1 = pb[1];
            bf1[0]=(short)f2bf(b0.x); bf1[1]=(short)f2bf(b0.y); bf1[2]=(short)f2bf(b0.z); bf1[3]=(short)f2bf(b0.w);
            bf1[4]=(short)f2bf(b1.x); bf1[5]=(short)f2bf(b1.y); bf1[6]=(short)f2bf(b1.z); bf1[7]=(short)f2bf(b1.w);
        }
        acc0 = __builtin_amdgcn_mfma_f32_16x16x32_bf16(af, bf0, acc0, 0, 0, 0);
        acc1 = __builtin_amdgcn_mfma_f32_16x16x32_bf16(af, bf1, acc1, 0, 0, 0);
    }

    // C/D layout (m89-verified): col = lane&15, row = (lane>>4)*4 + reg
    #pragma unroll
    for (int r = 0; r < 4; ++r) {
        red[wv][4 * g + r][l15]      = acc0[r];
        red[wv][4 * g + r][l15 + 16] = acc1[r];
    }
    __syncthreads();

    // Sum 4 wave-partials -> fold cpw (seq only) -> bf16 pack -> 4B store.
    const int o = tid * 2;
    const float* rf = &red[0][0][0];
    float vx = rf[o]     + rf[512 + o]     + rf[1024 + o]     + rf[1536 + o];
    float vy = rf[o + 1] + rf[512 + o + 1] + rf[1024 + o + 1] + rf[1536 + o + 1];
    if (!hid) {
        f32x2 w = *(const f32x2*)(cpw + (o & 31));
        vx *= w.x; vy *= w.y;
    }
    unsigned pk = (unsigned)f2bf(vx) | ((unsigned)f2bf(vy) << 16);
    unsigned short* Eo = E16 + (hid ? (size_t)4096 * 32 : 0) + (size_t)m0 * 32 + o;
    *(unsigned*)Eo = pk;
}

// K3: rank-32 GEMM via MFMA, zero LDS. REWORKED for coalesced stores + occupancy:
//  - B-fragment j loads hid row (4*l15 + j)  [instead of j*16+l15], so for fixed
//    (g,r) a lane's 4 accs are output cols 4*l15+{0..3} -> ONE f32x4 store;
//    each 16-lane group writes 256B contiguous (was 16 scattered dwords/64B).
//  - Wave tile 16s x 64h (1 A-frag, 4 B-frags, 4 MFMAs, 4 x4-stores);
//    block = 64s x 64h, grid (16,16,4) = 1024 blocks = 16 waves/CU (was 8).
// D[row][col]: col=lane&15 selects B-frag's col index -> h = h0 + 4*(lane&15)+j;
// row = s0 + 4*(lane>>4) + reg. Same kg(g,j)=8g+j k-slot map on both operands.
__global__ __launch_bounds__(256) void k3(const unsigned short* __restrict__ E16,
                                          float* __restrict__ out)
{
    const int tid = threadIdx.x;
    const int wv  = tid >> 6;
    const int l   = tid & 63;
    const int l15 = l & 15;
    const int g   = l >> 4;
    const int b   = blockIdx.z;
    const int s0  = blockIdx.y * 64 + wv * 16;
    const int h0  = blockIdx.x * 64;

    const unsigned short* As = E16 + ((size_t)(b * 1024 + s0)) * 32;
    const unsigned short* Bh = E16 + (size_t)4096 * 32 + ((size_t)(b * 1024 + h0)) * 32;

    bf16x8 af = *(const bf16x8*)(As + (size_t)l15 * 32 + g * 8);
    bf16x8 bfr[4];
    #pragma unroll
    for (int j = 0; j < 4; ++j)
        bfr[j] = *(const bf16x8*)(Bh + (size_t)(4 * l15 + j) * 32 + g * 8);

    const f32x4 zero = {0.f, 0.f, 0.f, 0.f};
    f32x4 acc[4];
    #pragma unroll
    for (int j = 0; j < 4; ++j)
        acc[j] = __builtin_amdgcn_mfma_f32_16x16x32_bf16(af, bfr[j], zero, 0, 0, 0);

    #pragma unroll
    for (int r = 0; r < 4; ++r) {
        f32x4 v = { acc[0][r], acc[1][r], acc[2][r], acc[3][r] };
        float* orow = out + ((size_t)(b * 1024 + s0 + 4 * g + r)) * 1024 + h0 + 4 * l15;
        *(f32x4*)orow = v;
    }
}

extern "C" void kernel_launch(void* const* d_in, const int* in_sizes, int n_in,
                              void* d_out, int out_size, void* d_ws, size_t ws_size,
                              hipStream_t stream) {
    const float* hs   = (const float*)d_in[0];
    // d_in[1] = all_indices: identically (n/H, n%H) -> computed implicitly
    const float* seqW = (const float*)d_in[2];
    const float* hidW = (const float*)d_in[3];
    const float* cpw  = (const float*)d_in[4];
    float* out = (float*)d_out;

    unsigned short* E16 = (unsigned short*)d_ws;   // [2][4096][32] bf16, 512 KB

    gemm_fused<<<512, 256, 0, stream>>>(hs, seqW, hidW, cpw, E16);
    dim3 grid3(16, 16, 4);
    k3<<<grid3, 256, 0, stream>>>(E16, out);
}